// Round 1
// baseline (409.766 us; speedup 1.0000x reference)
//
#include <hip/hip_runtime.h>
#include <hip/hip_bf16.h>
#include <stdint.h>

#define B_ 8
#define NTOK 7225
#define MTOT (B_*NTOK)      // 57800
#define MROWS 58368         // padded rows for all M-row buffers
#define RT_FULL 452         // ceil(57800/128)
#define RT_BATCH 57         // ceil(7225/128)

typedef unsigned short u16;
typedef u16 u16x8 __attribute__((ext_vector_type(8)));
typedef u16 u16x4 __attribute__((ext_vector_type(4)));
typedef __bf16 bf16x8 __attribute__((ext_vector_type(8)));
typedef float f32x4 __attribute__((ext_vector_type(4)));

__device__ inline float bf2f(u16 u){ union{float f;uint32_t i;}c; c.i=((uint32_t)u)<<16; return c.f; }
__device__ inline u16 f2bf(float f){ union{float f;uint32_t i;}c; c.f=f; uint32_t x=c.i;
                                     return (u16)((x + 0x7fffu + ((x>>16)&1u))>>16); }
__device__ inline float gelu_f(float x){
  float x3 = x*x*x;
  return 0.5f*x*(1.0f + tanhf(0.7978845608028654f*(x + 0.044715f*x3)));
}

__device__ inline void gload_lds16(const u16* g, u16* l) {
  __builtin_amdgcn_global_load_lds(
      (__attribute__((address_space(1))) void*)(const_cast<u16*>(g)),
      (__attribute__((address_space(3))) void*)(l), 16, 0, 0);
}

// ---------------- GEMM: C[M,N] = A[M,K](bf16) * B^T-layout[N,K](bf16) + epilogue --------------
// EPI 0: out bf16 = acc + bias
// EPI 1: out bf16 = gelu(acc + bias)
// EPI 2: out f32  = acc + bias + res
template<int EPI>
__global__ __launch_bounds__(256)
void gemm_bt(const u16* __restrict__ A, int lda,
             const u16* __restrict__ B, int ldb, int bStride,
             const float* __restrict__ bias,
             const float* __restrict__ res,
             void* __restrict__ outp, int ldo,
             int K, int rowsValid, int batchRowStride)
{
  __shared__ alignas(16) u16 As[2][128][32];
  __shared__ alignas(16) u16 Bs[2][128][32];
  const int tid = threadIdx.x;
  const int wid = tid >> 6;
  const int lane = tid & 63;
  const int bx = blockIdx.x, by = blockIdx.y, bz = blockIdx.z;
  const long rowBase = (long)bz * batchRowStride + (long)bx * 128;
  const int colBase = by * 128;
  const u16* Bp = B + (long)bz * bStride;

  const int srow = lane >> 2;        // 0..15
  const int scol = (lane & 3) * 8;   // 0,8,16,24
  const int NTk = K >> 5;

  auto stage = [&](int bf, int kt) {
    const int k0 = kt << 5;
#pragma unroll
    for (int i = 0; i < 2; ++i) {
      int r = wid*32 + i*16 + srow;
      gload_lds16(A + (rowBase + r)*(long)lda + k0 + scol, &As[bf][wid*32 + i*16][0]);
    }
#pragma unroll
    for (int i = 0; i < 2; ++i) {
      int r = wid*32 + i*16 + srow;
      gload_lds16(Bp + (long)(colBase + r)*ldb + k0 + scol, &Bs[bf][wid*32 + i*16][0]);
    }
  };

  f32x4 acc[4][4] = {};
  const int wm = wid >> 1, wn = wid & 1;
  const int lr = lane & 15;
  const int lk = (lane >> 4) * 8;

  stage(0, 0);
  for (int kt = 0; kt < NTk; ++kt) {
    const int bf = kt & 1;
    __syncthreads();                       // drains staging of buf bf (vmcnt0 before barrier)
    if (kt + 1 < NTk) stage(bf ^ 1, kt + 1);
    bf16x8 a[4], b[4];
#pragma unroll
    for (int mi = 0; mi < 4; ++mi)
      a[mi] = *reinterpret_cast<const bf16x8*>(&As[bf][wm*64 + mi*16 + lr][lk]);
#pragma unroll
    for (int ni = 0; ni < 4; ++ni)
      b[ni] = *reinterpret_cast<const bf16x8*>(&Bs[bf][wn*64 + ni*16 + lr][lk]);
#pragma unroll
    for (int mi = 0; mi < 4; ++mi)
#pragma unroll
      for (int ni = 0; ni < 4; ++ni)
        acc[mi][ni] = __builtin_amdgcn_mfma_f32_16x16x32_bf16(a[mi], b[ni], acc[mi][ni], 0, 0, 0);
  }

  // epilogue: C/D layout col=lane&15, row=(lane>>4)*4+reg  [measured m89]
  const int cr = (lane >> 4) * 4;
  const int cc = lane & 15;
#pragma unroll
  for (int mi = 0; mi < 4; ++mi) {
#pragma unroll
    for (int j = 0; j < 4; ++j) {
      const int r = wm*64 + mi*16 + cr + j;
      if (bx*128 + r < rowsValid) {
        const long grow = rowBase + r;
#pragma unroll
        for (int ni = 0; ni < 4; ++ni) {
          const int c = colBase + wn*64 + ni*16 + cc;
          float v = acc[mi][ni][j] + bias[c];
          const long oidx = grow*(long)ldo + c;
          if (EPI == 0)      ((u16*)outp)[oidx] = f2bf(v);
          else if (EPI == 1) ((u16*)outp)[oidx] = f2bf(gelu_f(v));
          else               ((float*)outp)[oidx] = v + res[oidx];
        }
      }
    }
  }
}

// ---------------- LayerNorm over C=256, one wave per token, bf16 out ----------------
__global__ __launch_bounds__(256)
void ln_kernel(const float* __restrict__ in, const float* __restrict__ g,
               const float* __restrict__ bt, u16* __restrict__ out, int M)
{
  const int wv = threadIdx.x >> 6, lane = threadIdx.x & 63;
  const int t = blockIdx.x * 4 + wv;
  if (t >= M) return;
  const float4 x = reinterpret_cast<const float4*>(in + (long)t*256)[lane];
  float s = x.x + x.y + x.z + x.w;
  float q = x.x*x.x + x.y*x.y + x.z*x.z + x.w*x.w;
#pragma unroll
  for (int o = 32; o > 0; o >>= 1) { s += __shfl_xor(s, o); q += __shfl_xor(q, o); }
  const float m  = s * (1.0f/256.0f);
  const float var = q * (1.0f/256.0f) - m*m;
  const float rs = rsqrtf(var + 1e-5f);
  const float4 gv = reinterpret_cast<const float4*>(g)[lane];
  const float4 bv = reinterpret_cast<const float4*>(bt)[lane];
  u16x4 o4;
  o4[0] = f2bf((x.x - m)*rs*gv.x + bv.x);
  o4[1] = f2bf((x.y - m)*rs*gv.y + bv.y);
  o4[2] = f2bf((x.z - m)*rs*gv.z + bv.z);
  o4[3] = f2bf((x.w - m)*rs*gv.w + bv.w);
  *reinterpret_cast<u16x4*>(out + (long)t*256 + lane*4) = o4;
}

// -------- fused per-head LN(k), LN(v) + kv[b,h] += k^T v / N (atomic f32) --------
__global__ __launch_bounds__(256)
void kv_kernel(const u16* __restrict__ QKV,
               const float* __restrict__ kg, const float* __restrict__ kb,
               const float* __restrict__ vg, const float* __restrict__ vb,
               float* __restrict__ kvout)
{
  const int bh = blockIdx.x, b = bh >> 3, h = bh & 7;
  const int tid = threadIdx.x;
  __shared__ u16 kls[256][32];
  __shared__ u16 vls[256][32];
  __shared__ float sg[4][32];
  if (tid < 32) {
    sg[0][tid] = kg[h*32 + tid];
    sg[1][tid] = kb[h*32 + tid];
    sg[2][tid] = vg[h*32 + tid];
    sg[3][tid] = vb[h*32 + tid];
  }
  const int d = tid >> 3, e0 = (tid & 7) * 4;
  float a0=0, a1=0, a2=0, a3=0;

  for (int sub = 0; sub < 2; ++sub) {
    const int r = blockIdx.y * 512 + sub * 256 + tid;
    __syncthreads();
    if (r < NTOK) {
      const u16* rowp = QKV + (long)(b*NTOK + r)*768;
#pragma unroll
      for (int kv2 = 0; kv2 < 2; ++kv2) {
        const u16* p = rowp + (kv2 ? 512 : 256) + h*32;
        float xv[32]; float s = 0.f;
#pragma unroll
        for (int q4 = 0; q4 < 4; ++q4) {
          u16x8 u = *reinterpret_cast<const u16x8*>(p + q4*8);
#pragma unroll
          for (int j = 0; j < 8; ++j) { float f = bf2f(u[j]); xv[q4*8+j] = f; s += f; }
        }
        const float m = s * (1.0f/32.0f);
        float vv = 0.f;
#pragma unroll
        for (int j = 0; j < 32; ++j) { float d2 = xv[j]-m; vv += d2*d2; }
        const float rs = rsqrtf(vv*(1.0f/32.0f) + 1e-5f);
        const float* gg = sg[kv2 ? 2 : 0];
        const float* bb = sg[kv2 ? 3 : 1];
        u16 (*dst)[32] = kv2 ? vls : kls;
#pragma unroll
        for (int j = 0; j < 32; ++j) dst[tid][j] = f2bf((xv[j]-m)*rs*gg[j] + bb[j]);
      }
    } else {
#pragma unroll
      for (int j = 0; j < 32; ++j) { kls[tid][j] = 0; vls[tid][j] = 0; }
    }
    __syncthreads();
#pragma unroll 4
    for (int rr = 0; rr < 256; ++rr) {
      const float kd = bf2f(kls[rr][d]);
      u16x4 v4 = *reinterpret_cast<const u16x4*>(&vls[rr][e0]);
      a0 += kd * bf2f(v4[0]); a1 += kd * bf2f(v4[1]);
      a2 += kd * bf2f(v4[2]); a3 += kd * bf2f(v4[3]);
    }
  }
  const float sc = 1.0f / (float)NTOK;
  float* o = kvout + (long)bh*1024 + d*32 + e0;
  atomicAdd(o+0, a0*sc); atomicAdd(o+1, a1*sc);
  atomicAdd(o+2, a2*sc); atomicAdd(o+3, a3*sc);
}

// -------- Wo_eff_t[b][c][r=h*32+d] = sum_e kv[b,h,d,e] * Wo[h*32+e][c] (bf16, B^T layout) -----
__global__ __launch_bounds__(256)
void woeff_kernel(const float* __restrict__ kv, const float* __restrict__ Wo,
                  u16* __restrict__ Woet)
{
  const int b = blockIdx.x >> 8, c = blockIdx.x & 255;
  const int rtid = threadIdx.x;
  const int h = rtid >> 5, dd = rtid & 31;
  const float* kvp = kv + ((long)(b*8 + h)*32 + dd)*32;
  float s = 0.f;
#pragma unroll 8
  for (int e = 0; e < 32; ++e) s += kvp[e] * Wo[(h*32 + e)*256 + c];
  Woet[(long)(b*256 + c)*256 + rtid] = f2bf(s);
}

// ---------------- prep kernels ----------------
__global__ void zero_f32(float* p, int n) {
  int i = blockIdx.x*blockDim.x + threadIdx.x; if (i < n) p[i] = 0.f;
}
__global__ void concat_bias(const float* bq, const float* bk, const float* bv, float* o) {
  int i = threadIdx.x;
  o[i] = (i < 256) ? bq[i] : ((i < 512) ? bk[i-256] : bv[i-512]);
}
__global__ __launch_bounds__(256)
void transpose_cvt(const float* __restrict__ src, u16* __restrict__ dst, int R, int C) {
  __shared__ float t[32][33];
  const int tc = blockIdx.x * 32, tr = blockIdx.y * 32;
  const int lx = threadIdx.x & 31, ly = threadIdx.x >> 5;
#pragma unroll
  for (int i = 0; i < 32; i += 8)
    t[ly + i][lx] = src[(long)(tr + ly + i)*C + tc + lx];
  __syncthreads();
#pragma unroll
  for (int i = 0; i < 32; i += 8)
    dst[(long)(tc + ly + i)*R + tr + lx] = f2bf(t[lx][ly + i]);
}

// ---------------- launch ----------------
extern "C" void kernel_launch(void* const* d_in, const int* in_sizes, int n_in,
                              void* d_out, int out_size, void* d_ws, size_t ws_size,
                              hipStream_t stream)
{
  const float* fx    = (const float*)d_in[0];
  const float* ln1_g = (const float*)d_in[1];
  const float* ln1_b = (const float*)d_in[2];
  const float* Wq = (const float*)d_in[3];
  const float* bq = (const float*)d_in[4];
  const float* Wk = (const float*)d_in[5];
  const float* bk = (const float*)d_in[6];
  const float* Wv = (const float*)d_in[7];
  const float* bv = (const float*)d_in[8];
  const float* Wo = (const float*)d_in[9];
  const float* bo = (const float*)d_in[10];
  const float* kg  = (const float*)d_in[11];
  const float* kbb = (const float*)d_in[12];
  const float* vg  = (const float*)d_in[13];
  const float* vbb = (const float*)d_in[14];
  const float* ln2_g = (const float*)d_in[15];
  const float* ln2_b = (const float*)d_in[16];
  const float* W1 = (const float*)d_in[17];
  const float* b1 = (const float*)d_in[18];
  const float* W2 = (const float*)d_in[19];
  const float* b2 = (const float*)d_in[20];
  float* outF = (float*)d_out;

  char* ws = (char*)d_ws;
  size_t off = 0;
  auto alloc = [&](size_t bytes) { char* p = ws + off; off += (bytes + 255) & ~(size_t)255; return p; };
  u16* bufX   = (u16*)alloc((size_t)MROWS*256*2);
  u16* bufQKV = (u16*)alloc((size_t)MROWS*768*2);
  u16* bufH   = (u16*)alloc((size_t)MROWS*1024*2);
  u16* Wqkv_t = (u16*)alloc(768*256*2);
  u16* W1_t   = (u16*)alloc(1024*256*2);
  u16* W2_t   = (u16*)alloc(256*1024*2);
  u16* Woe_t  = (u16*)alloc((size_t)8*256*256*2);
  float* kvb  = (float*)alloc((size_t)64*1024*4);
  float* bqkv = (float*)alloc(768*4);
  (void)ws_size; (void)out_size; (void)n_in; (void)in_sizes;

  // prep
  zero_f32<<<256, 256, 0, stream>>>(kvb, 65536);
  concat_bias<<<1, 768, 0, stream>>>(bq, bk, bv, bqkv);
  transpose_cvt<<<dim3(8,8),  256, 0, stream>>>(Wq, Wqkv_t,          256, 256);
  transpose_cvt<<<dim3(8,8),  256, 0, stream>>>(Wk, Wqkv_t + 65536,  256, 256);
  transpose_cvt<<<dim3(8,8),  256, 0, stream>>>(Wv, Wqkv_t + 131072, 256, 256);
  transpose_cvt<<<dim3(32,8), 256, 0, stream>>>(W1, W1_t, 256, 1024);
  transpose_cvt<<<dim3(8,32), 256, 0, stream>>>(W2, W2_t, 1024, 256);

  // x = LN1(fx)
  ln_kernel<<<MTOT/4, 256, 0, stream>>>(fx, ln1_g, ln1_b, bufX, MTOT);

  // QKV = x @ [Wq|Wk|Wv] + [bq|bk|bv]
  gemm_bt<0><<<dim3(RT_FULL, 6, 1), 256, 0, stream>>>(
      bufX, 256, Wqkv_t, 256, 0, bqkv, nullptr, bufQKV, 768, 256, 1<<30, 0);

  // kv[b,h] = LN(k)^T LN(v) / N
  kv_kernel<<<dim3(64, 15), 256, 0, stream>>>(bufQKV, kg, kbb, vg, vbb, kvb);

  // Wo_eff per batch
  woeff_kernel<<<2048, 256, 0, stream>>>(kvb, Wo, Woe_t);

  // d_out = fx + q @ Wo_eff[b] + bo   (batched GEMM)
  gemm_bt<2><<<dim3(RT_BATCH, 2, 8), 256, 0, stream>>>(
      bufQKV, 768, Woe_t, 256, 65536, bo, fx, outF, 256, 256, NTOK, NTOK);

  // x2 = LN2(d_out)
  ln_kernel<<<MTOT/4, 256, 0, stream>>>(outF, ln2_g, ln2_b, bufX, MTOT);

  // H = gelu(x2 @ W1 + b1)
  gemm_bt<1><<<dim3(RT_FULL, 8, 1), 256, 0, stream>>>(
      bufX, 256, W1_t, 256, 0, b1, nullptr, bufH, 1024, 256, 1<<30, 0);

  // d_out = d_out + H @ W2 + b2
  gemm_bt<2><<<dim3(RT_FULL, 2, 1), 256, 0, stream>>>(
      bufH, 1024, W2_t, 1024, 0, b2, outF, outF, 256, 1024, MTOT, 0);
}

// Round 2
// 352.977 us; speedup vs baseline: 1.1609x; 1.1609x over previous
//
#include <hip/hip_runtime.h>
#include <hip/hip_bf16.h>
#include <stdint.h>

#define B_ 8
#define NTOK 7225
#define MTOT (B_*NTOK)      // 57800
#define MROWS 58368         // padded rows for all M-row buffers
#define RT_FULL 452         // ceil(57800/128)
#define RT_BATCH 57         // ceil(7225/128)

typedef unsigned short u16;
typedef u16 u16x8 __attribute__((ext_vector_type(8)));
typedef u16 u16x4 __attribute__((ext_vector_type(4)));
typedef __bf16 bf16x8 __attribute__((ext_vector_type(8)));
typedef float f32x4 __attribute__((ext_vector_type(4)));

__device__ inline float bf2f(u16 u){ union{float f;uint32_t i;}c; c.i=((uint32_t)u)<<16; return c.f; }
__device__ inline u16 f2bf(float f){ union{float f;uint32_t i;}c; c.f=f; uint32_t x=c.i;
                                     return (u16)((x + 0x7fffu + ((x>>16)&1u))>>16); }
// fast tanh-gelu: 0.5x(1+tanh t) == x * (1 - 1/(exp(2t)+1)); exact limits at +-inf
__device__ inline float gelu_f(float x){
  float t = 0.7978845608028654f * x * (1.0f + 0.044715f*x*x);
  float e = __expf(2.0f*t);
  return x * (1.0f - 1.0f/(e + 1.0f));
}

__device__ inline void gload_lds16(const u16* g, u16* l) {
  __builtin_amdgcn_global_load_lds(
      (__attribute__((address_space(1))) void*)(const_cast<u16*>(g)),
      (__attribute__((address_space(3))) void*)(l), 16, 0, 0);
}

// ---------------- GEMM: C[M,N] = A[M,K](bf16) * B^T-layout[N,K](bf16) + epilogue --------------
// EPI 0: out bf16 = acc + bias
// EPI 1: out bf16 = gelu(acc + bias)
// EPI 2: out f32  = acc + bias + res
// LDS tiles are slot-swizzled: phys_slot = log_slot ^ ((row>>1)&3)  (slot = 16B = 8 bf16)
// -> quarter-wave ds_read_b128 hits 8 distinct (bank-hi, slot) combos = 2-way alias = free.
// Staging keeps LDS dest linear (global_load_lds constraint) and pre-swizzles the GLOBAL col.
template<int EPI>
__global__ __launch_bounds__(256)
void gemm_bt(const u16* __restrict__ A, int lda,
             const u16* __restrict__ B, int ldb, int bStride,
             const float* __restrict__ bias,
             const float* __restrict__ res,
             void* __restrict__ outp, int ldo,
             int K, int rowsValid, int batchRowStride)
{
  __shared__ alignas(16) u16 As[2][128][32];
  __shared__ alignas(16) u16 Bs[2][128][32];
  const int tid = threadIdx.x;
  const int wid = tid >> 6;
  const int lane = tid & 63;

  // --- bijective XCD swizzle (m204): contiguous swz chunk per XCD, y-fastest within chunk
  const int gx = gridDim.x, gy = gridDim.y;
  const int n = gx * gy;
  const int flat = blockIdx.y * gx + blockIdx.x;
  const int qq = n >> 3, rr = n & 7;
  const int xcd = flat & 7, pos = flat >> 3;
  const int swz = (xcd < rr ? xcd*(qq+1) : rr*(qq+1) + (xcd-rr)*qq) + pos;
  const int bx = swz / gy, by = swz % gy;

  const int bz = blockIdx.z;
  const long rowBase = (long)bz * batchRowStride + (long)bx * 128;
  const int colBase = by * 128;
  const u16* Bp = B + (long)bz * bStride;

  const int srow = lane >> 2;                             // 0..15
  const int scol = ((lane & 3) ^ ((lane >> 3) & 3)) * 8;  // pre-swizzled global slot
  const int NTk = K >> 5;

  auto stage = [&](int bf, int kt) {
    const int k0 = kt << 5;
#pragma unroll
    for (int i = 0; i < 2; ++i) {
      int r = wid*32 + i*16 + srow;
      gload_lds16(A + (rowBase + r)*(long)lda + k0 + scol, &As[bf][wid*32 + i*16][0]);
    }
#pragma unroll
    for (int i = 0; i < 2; ++i) {
      int r = wid*32 + i*16 + srow;
      gload_lds16(Bp + (long)(colBase + r)*ldb + k0 + scol, &Bs[bf][wid*32 + i*16][0]);
    }
  };

  f32x4 acc[4][4] = {};
  const int wm = wid >> 1, wn = wid & 1;
  const int lr = lane & 15;
  const int sl = lane >> 4;            // logical 16B slot (k-quarter)

  stage(0, 0);
  for (int kt = 0; kt < NTk; ++kt) {
    const int bf = kt & 1;
    __syncthreads();                       // drains staging of buf bf
    if (kt + 1 < NTk) stage(bf ^ 1, kt + 1);
    bf16x8 a[4], b[4];
#pragma unroll
    for (int mi = 0; mi < 4; ++mi) {
      const int r = wm*64 + mi*16 + lr;
      const int sp = sl ^ ((r >> 1) & 3);
      a[mi] = *reinterpret_cast<const bf16x8*>(&As[bf][r][sp*8]);
    }
#pragma unroll
    for (int ni = 0; ni < 4; ++ni) {
      const int r = wn*64 + ni*16 + lr;
      const int sp = sl ^ ((r >> 1) & 3);
      b[ni] = *reinterpret_cast<const bf16x8*>(&Bs[bf][r][sp*8]);
    }
#pragma unroll
    for (int mi = 0; mi < 4; ++mi)
#pragma unroll
      for (int ni = 0; ni < 4; ++ni)
        acc[mi][ni] = __builtin_amdgcn_mfma_f32_16x16x32_bf16(a[mi], b[ni], acc[mi][ni], 0, 0, 0);
  }

  // epilogue: C/D layout col=lane&15, row=(lane>>4)*4+reg  [measured m89]
  const int cr = (lane >> 4) * 4;
  const int cc = lane & 15;
#pragma unroll
  for (int mi = 0; mi < 4; ++mi) {
#pragma unroll
    for (int j = 0; j < 4; ++j) {
      const int r = wm*64 + mi*16 + cr + j;
      if (bx*128 + r < rowsValid) {
        const long grow = rowBase + r;
#pragma unroll
        for (int ni = 0; ni < 4; ++ni) {
          const int c = colBase + wn*64 + ni*16 + cc;
          float v = acc[mi][ni][j] + bias[c];
          const long oidx = grow*(long)ldo + c;
          if (EPI == 0)      ((u16*)outp)[oidx] = f2bf(v);
          else if (EPI == 1) ((u16*)outp)[oidx] = f2bf(gelu_f(v));
          else               ((float*)outp)[oidx] = v + res[oidx];
        }
      }
    }
  }
}

// ---------------- LayerNorm over C=256, one wave per token, bf16 out ----------------
__global__ __launch_bounds__(256)
void ln_kernel(const float* __restrict__ in, const float* __restrict__ g,
               const float* __restrict__ bt, u16* __restrict__ out, int M)
{
  const int wv = threadIdx.x >> 6, lane = threadIdx.x & 63;
  const int t = blockIdx.x * 4 + wv;
  if (t >= M) return;
  const float4 x = reinterpret_cast<const float4*>(in + (long)t*256)[lane];
  float s = x.x + x.y + x.z + x.w;
  float q = x.x*x.x + x.y*x.y + x.z*x.z + x.w*x.w;
#pragma unroll
  for (int o = 32; o > 0; o >>= 1) { s += __shfl_xor(s, o); q += __shfl_xor(q, o); }
  const float m  = s * (1.0f/256.0f);
  const float var = q * (1.0f/256.0f) - m*m;
  const float rs = rsqrtf(var + 1e-5f);
  const float4 gv = reinterpret_cast<const float4*>(g)[lane];
  const float4 bv = reinterpret_cast<const float4*>(bt)[lane];
  u16x4 o4;
  o4[0] = f2bf((x.x - m)*rs*gv.x + bv.x);
  o4[1] = f2bf((x.y - m)*rs*gv.y + bv.y);
  o4[2] = f2bf((x.z - m)*rs*gv.z + bv.z);
  o4[3] = f2bf((x.w - m)*rs*gv.w + bv.w);
  *reinterpret_cast<u16x4*>(out + (long)t*256 + lane*4) = o4;
}

// -------- fused per-head LN(k), LN(v) + kv[b,h] += k^T v / N (atomic f32) --------
__global__ __launch_bounds__(256)
void kv_kernel(const u16* __restrict__ QKV,
               const float* __restrict__ kg, const float* __restrict__ kb,
               const float* __restrict__ vg, const float* __restrict__ vb,
               float* __restrict__ kvout)
{
  const int bh = blockIdx.x, b = bh >> 3, h = bh & 7;
  const int tid = threadIdx.x;
  __shared__ u16 kls[256][32];
  __shared__ u16 vls[256][32];
  __shared__ float sg[4][32];
  if (tid < 32) {
    sg[0][tid] = kg[h*32 + tid];
    sg[1][tid] = kb[h*32 + tid];
    sg[2][tid] = vg[h*32 + tid];
    sg[3][tid] = vb[h*32 + tid];
  }
  const int d = tid >> 3, e0 = (tid & 7) * 4;
  float a0=0, a1=0, a2=0, a3=0;

  for (int sub = 0; sub < 2; ++sub) {
    const int r = blockIdx.y * 512 + sub * 256 + tid;
    __syncthreads();
    if (r < NTOK) {
      const u16* rowp = QKV + (long)(b*NTOK + r)*768;
#pragma unroll
      for (int kv2 = 0; kv2 < 2; ++kv2) {
        const u16* p = rowp + (kv2 ? 512 : 256) + h*32;
        float xv[32]; float s = 0.f;
#pragma unroll
        for (int q4 = 0; q4 < 4; ++q4) {
          u16x8 u = *reinterpret_cast<const u16x8*>(p + q4*8);
#pragma unroll
          for (int j = 0; j < 8; ++j) { float f = bf2f(u[j]); xv[q4*8+j] = f; s += f; }
        }
        const float m = s * (1.0f/32.0f);
        float vv = 0.f;
#pragma unroll
        for (int j = 0; j < 32; ++j) { float d2 = xv[j]-m; vv += d2*d2; }
        const float rs = rsqrtf(vv*(1.0f/32.0f) + 1e-5f);
        const float* gg = sg[kv2 ? 2 : 0];
        const float* bb = sg[kv2 ? 3 : 1];
        u16 (*dst)[32] = kv2 ? vls : kls;
#pragma unroll
        for (int j = 0; j < 32; ++j) dst[tid][j] = f2bf((xv[j]-m)*rs*gg[j] + bb[j]);
      }
    } else {
#pragma unroll
      for (int j = 0; j < 32; ++j) { kls[tid][j] = 0; vls[tid][j] = 0; }
    }
    __syncthreads();
#pragma unroll 4
    for (int rr = 0; rr < 256; ++rr) {
      const float kd = bf2f(kls[rr][d]);
      u16x4 v4 = *reinterpret_cast<const u16x4*>(&vls[rr][e0]);
      a0 += kd * bf2f(v4[0]); a1 += kd * bf2f(v4[1]);
      a2 += kd * bf2f(v4[2]); a3 += kd * bf2f(v4[3]);
    }
  }
  const float sc = 1.0f / (float)NTOK;
  float* o = kvout + (long)bh*1024 + d*32 + e0;
  atomicAdd(o+0, a0*sc); atomicAdd(o+1, a1*sc);
  atomicAdd(o+2, a2*sc); atomicAdd(o+3, a3*sc);
}

// -------- Wo_eff_t[b][c][r=h*32+d] = sum_e kv[b,h,d,e] * Wo[h*32+e][c] (bf16, B^T layout) -----
__global__ __launch_bounds__(256)
void woeff_kernel(const float* __restrict__ kv, const float* __restrict__ Wo,
                  u16* __restrict__ Woet)
{
  const int b = blockIdx.x >> 8, c = blockIdx.x & 255;
  const int rtid = threadIdx.x;
  const int h = rtid >> 5, dd = rtid & 31;
  const float* kvp = kv + ((long)(b*8 + h)*32 + dd)*32;
  float s = 0.f;
#pragma unroll 8
  for (int e = 0; e < 32; ++e) s += kvp[e] * Wo[(h*32 + e)*256 + c];
  Woet[(long)(b*256 + c)*256 + rtid] = f2bf(s);
}

// ---------------- prep kernels ----------------
__global__ void zero_f32(float* p, int n) {
  int i = blockIdx.x*blockDim.x + threadIdx.x; if (i < n) p[i] = 0.f;
}
__global__ void concat_bias(const float* bq, const float* bk, const float* bv, float* o) {
  int i = threadIdx.x;
  o[i] = (i < 256) ? bq[i] : ((i < 512) ? bk[i-256] : bv[i-512]);
}
__global__ __launch_bounds__(256)
void transpose_cvt(const float* __restrict__ src, u16* __restrict__ dst, int R, int C) {
  __shared__ float t[32][33];
  const int tc = blockIdx.x * 32, tr = blockIdx.y * 32;
  const int lx = threadIdx.x & 31, ly = threadIdx.x >> 5;
#pragma unroll
  for (int i = 0; i < 32; i += 8)
    t[ly + i][lx] = src[(long)(tr + ly + i)*C + tc + lx];
  __syncthreads();
#pragma unroll
  for (int i = 0; i < 32; i += 8)
    dst[(long)(tc + ly + i)*R + tr + lx] = f2bf(t[lx][ly + i]);
}

// ---------------- launch ----------------
extern "C" void kernel_launch(void* const* d_in, const int* in_sizes, int n_in,
                              void* d_out, int out_size, void* d_ws, size_t ws_size,
                              hipStream_t stream)
{
  const float* fx    = (const float*)d_in[0];
  const float* ln1_g = (const float*)d_in[1];
  const float* ln1_b = (const float*)d_in[2];
  const float* Wq = (const float*)d_in[3];
  const float* bq = (const float*)d_in[4];
  const float* Wk = (const float*)d_in[5];
  const float* bk = (const float*)d_in[6];
  const float* Wv = (const float*)d_in[7];
  const float* bv = (const float*)d_in[8];
  const float* Wo = (const float*)d_in[9];
  const float* bo = (const float*)d_in[10];
  const float* kg  = (const float*)d_in[11];
  const float* kbb = (const float*)d_in[12];
  const float* vg  = (const float*)d_in[13];
  const float* vbb = (const float*)d_in[14];
  const float* ln2_g = (const float*)d_in[15];
  const float* ln2_b = (const float*)d_in[16];
  const float* W1 = (const float*)d_in[17];
  const float* b1 = (const float*)d_in[18];
  const float* W2 = (const float*)d_in[19];
  const float* b2 = (const float*)d_in[20];
  float* outF = (float*)d_out;

  char* ws = (char*)d_ws;
  size_t off = 0;
  auto alloc = [&](size_t bytes) { char* p = ws + off; off += (bytes + 255) & ~(size_t)255; return p; };
  u16* bufX   = (u16*)alloc((size_t)MROWS*256*2);
  u16* bufQKV = (u16*)alloc((size_t)MROWS*768*2);
  u16* bufH   = (u16*)alloc((size_t)MROWS*1024*2);
  u16* Wqkv_t = (u16*)alloc(768*256*2);
  u16* W1_t   = (u16*)alloc(1024*256*2);
  u16* W2_t   = (u16*)alloc(256*1024*2);
  u16* Woe_t  = (u16*)alloc((size_t)8*256*256*2);
  float* kvb  = (float*)alloc((size_t)64*1024*4);
  float* bqkv = (float*)alloc(768*4);
  (void)ws_size; (void)out_size; (void)n_in; (void)in_sizes;

  // prep
  zero_f32<<<256, 256, 0, stream>>>(kvb, 65536);
  concat_bias<<<1, 768, 0, stream>>>(bq, bk, bv, bqkv);
  transpose_cvt<<<dim3(8,8),  256, 0, stream>>>(Wq, Wqkv_t,          256, 256);
  transpose_cvt<<<dim3(8,8),  256, 0, stream>>>(Wk, Wqkv_t + 65536,  256, 256);
  transpose_cvt<<<dim3(8,8),  256, 0, stream>>>(Wv, Wqkv_t + 131072, 256, 256);
  transpose_cvt<<<dim3(32,8), 256, 0, stream>>>(W1, W1_t, 256, 1024);
  transpose_cvt<<<dim3(8,32), 256, 0, stream>>>(W2, W2_t, 1024, 256);

  // x = LN1(fx)
  ln_kernel<<<MTOT/4, 256, 0, stream>>>(fx, ln1_g, ln1_b, bufX, MTOT);

  // QKV = x @ [Wq|Wk|Wv] + [bq|bk|bv]
  gemm_bt<0><<<dim3(RT_FULL, 6, 1), 256, 0, stream>>>(
      bufX, 256, Wqkv_t, 256, 0, bqkv, nullptr, bufQKV, 768, 256, 1<<30, 0);

  // kv[b,h] = LN(k)^T LN(v) / N
  kv_kernel<<<dim3(64, 15), 256, 0, stream>>>(bufQKV, kg, kbb, vg, vbb, kvb);

  // Wo_eff per batch
  woeff_kernel<<<2048, 256, 0, stream>>>(kvb, Wo, Woe_t);

  // d_out = fx + q @ Wo_eff[b] + bo   (batched GEMM)
  gemm_bt<2><<<dim3(RT_BATCH, 2, 8), 256, 0, stream>>>(
      bufQKV, 768, Woe_t, 256, 65536, bo, fx, outF, 256, 256, NTOK, NTOK);

  // x2 = LN2(d_out)
  ln_kernel<<<MTOT/4, 256, 0, stream>>>(outF, ln2_g, ln2_b, bufX, MTOT);

  // H = gelu(x2 @ W1 + b1)
  gemm_bt<1><<<dim3(RT_FULL, 8, 1), 256, 0, stream>>>(
      bufX, 256, W1_t, 256, 0, b1, nullptr, bufH, 1024, 256, 1<<30, 0);

  // d_out = d_out + H @ W2 + b2
  gemm_bt<2><<<dim3(RT_FULL, 2, 1), 256, 0, stream>>>(
      bufH, 1024, W2_t, 1024, 0, b2, outF, outF, 256, 1024, MTOT, 0);
}

// Round 3
// 331.395 us; speedup vs baseline: 1.2365x; 1.0651x over previous
//
#include <hip/hip_runtime.h>
#include <hip/hip_bf16.h>
#include <stdint.h>

#define B_ 8
#define NTOK 7225
#define MTOT (B_*NTOK)      // 57800
#define MROWS 58368         // padded rows for all M-row buffers
#define RT_FULL 452         // ceil(57800/128)
#define RT_BATCH 57         // ceil(7225/128)

typedef unsigned short u16;
typedef u16 u16x8 __attribute__((ext_vector_type(8)));
typedef u16 u16x4 __attribute__((ext_vector_type(4)));
typedef __bf16 bf16x8 __attribute__((ext_vector_type(8)));
typedef float f32x4 __attribute__((ext_vector_type(4)));

__device__ inline float bf2f(u16 u){ union{float f;uint32_t i;}c; c.i=((uint32_t)u)<<16; return c.f; }
__device__ inline u16 f2bf(float f){ union{float f;uint32_t i;}c; c.f=f; uint32_t x=c.i;
                                     return (u16)((x + 0x7fffu + ((x>>16)&1u))>>16); }
// packed f32x2 -> bf16x2 (RNE), S0 -> low half [guide T12 recipe]
__device__ inline uint32_t cvt_pk_bf16(float a, float b){
  uint32_t r; asm("v_cvt_pk_bf16_f32 %0, %1, %2" : "=v"(r) : "v"(a), "v"(b)); return r;
}
// fast tanh-gelu: 0.5x(1+tanh t) == x * (1 - 1/(exp(2t)+1)); rcp is 1-ulp, fine for bf16 out
__device__ inline float gelu_f(float x){
  float t = 0.7978845608028654f * x * (1.0f + 0.044715f*x*x);
  float e = __expf(2.0f*t);
  return x * (1.0f - __builtin_amdgcn_rcpf(e + 1.0f));
}

__device__ inline void gload_lds16(const u16* g, u16* l) {
  __builtin_amdgcn_global_load_lds(
      (__attribute__((address_space(1))) void*)(const_cast<u16*>(g)),
      (__attribute__((address_space(3))) void*)(l), 16, 0, 0);
}

// ---------------- GEMM: C[M,N] = A[M,K](bf16) * B^T-layout[N,K](bf16) + epilogue --------------
// EPI 0: out bf16 = acc + bias
// EPI 1: out bf16 = gelu(acc + bias)
// EPI 2: out f32  = acc + bias + res
// LDS slot-swizzled (phys_slot = log_slot ^ ((row>>1)&3)); staging pre-swizzles the GLOBAL col.
// MFMA called SWAPPED: mfma(b, a, acc) -> fragment holds C^T tile:
//   output row = lane&15 (fixed/lane), output col = (lane>>4)*4 + reg (4 consecutive!)
// -> vectorized 8B/16B stores instead of 64 scalar 2B stores per thread.
template<int EPI>
__global__ __launch_bounds__(256)
void gemm_bt(const u16* __restrict__ A, int lda,
             const u16* __restrict__ B, int ldb, int bStride,
             const float* __restrict__ bias,
             const float* __restrict__ res,
             void* __restrict__ outp, int ldo,
             int K, int rowsValid, int batchRowStride)
{
  __shared__ alignas(16) u16 As[2][128][32];
  __shared__ alignas(16) u16 Bs[2][128][32];
  const int tid = threadIdx.x;
  const int wid = tid >> 6;
  const int lane = tid & 63;

  // --- bijective XCD swizzle (m204): contiguous swz chunk per XCD, y-fastest within chunk
  const int gx = gridDim.x, gy = gridDim.y;
  const int n = gx * gy;
  const int flat = blockIdx.y * gx + blockIdx.x;
  const int qq = n >> 3, rr = n & 7;
  const int xcd = flat & 7, pos = flat >> 3;
  const int swz = (xcd < rr ? xcd*(qq+1) : rr*(qq+1) + (xcd-rr)*qq) + pos;
  const int bx = swz / gy, by = swz % gy;

  const int bz = blockIdx.z;
  const long rowBase = (long)bz * batchRowStride + (long)bx * 128;
  const int colBase = by * 128;
  const u16* Bp = B + (long)bz * bStride;

  const int srow = lane >> 2;                             // 0..15
  const int scol = ((lane & 3) ^ ((lane >> 3) & 3)) * 8;  // pre-swizzled global slot
  const int NTk = K >> 5;

  auto stage = [&](int bf, int kt) {
    const int k0 = kt << 5;
#pragma unroll
    for (int i = 0; i < 2; ++i) {
      int r = wid*32 + i*16 + srow;
      gload_lds16(A + (rowBase + r)*(long)lda + k0 + scol, &As[bf][wid*32 + i*16][0]);
    }
#pragma unroll
    for (int i = 0; i < 2; ++i) {
      int r = wid*32 + i*16 + srow;
      gload_lds16(Bp + (long)(colBase + r)*ldb + k0 + scol, &Bs[bf][wid*32 + i*16][0]);
    }
  };

  f32x4 acc[4][4] = {};
  const int wm = wid >> 1, wn = wid & 1;
  const int lr = lane & 15;
  const int sl = lane >> 4;            // logical 16B slot (k-quarter)

  stage(0, 0);
  for (int kt = 0; kt < NTk; ++kt) {
    const int bf = kt & 1;
    __syncthreads();                       // drains staging of buf bf
    if (kt + 1 < NTk) stage(bf ^ 1, kt + 1);
    bf16x8 a[4], b[4];
#pragma unroll
    for (int mi = 0; mi < 4; ++mi) {
      const int r = wm*64 + mi*16 + lr;
      const int sp = sl ^ ((r >> 1) & 3);
      a[mi] = *reinterpret_cast<const bf16x8*>(&As[bf][r][sp*8]);
    }
#pragma unroll
    for (int ni = 0; ni < 4; ++ni) {
      const int r = wn*64 + ni*16 + lr;
      const int sp = sl ^ ((r >> 1) & 3);
      b[ni] = *reinterpret_cast<const bf16x8*>(&Bs[bf][r][sp*8]);
    }
#pragma unroll
    for (int mi = 0; mi < 4; ++mi)
#pragma unroll
      for (int ni = 0; ni < 4; ++ni)   // swapped operands -> C^T fragment layout
        acc[mi][ni] = __builtin_amdgcn_mfma_f32_16x16x32_bf16(b[ni], a[mi], acc[mi][ni], 0, 0, 0);
  }

  // epilogue (swapped layout): row = lane&15, col = (lane>>4)*4 + j
  const int cq = (lane >> 4) * 4;
  f32x4 bv4[4];
#pragma unroll
  for (int ni = 0; ni < 4; ++ni)
    bv4[ni] = *reinterpret_cast<const f32x4*>(&bias[colBase + wn*64 + ni*16 + cq]);
#pragma unroll
  for (int mi = 0; mi < 4; ++mi) {
    const int r = wm*64 + mi*16 + lr;
    if (bx*128 + r < rowsValid) {
      const long grow = rowBase + r;
#pragma unroll
      for (int ni = 0; ni < 4; ++ni) {
        const int c0 = colBase + wn*64 + ni*16 + cq;
        const long oidx = grow*(long)ldo + c0;
        f32x4 v = acc[mi][ni] + bv4[ni];
        if (EPI == 0) {
          uint2 pk; pk.x = cvt_pk_bf16(v[0], v[1]); pk.y = cvt_pk_bf16(v[2], v[3]);
          *reinterpret_cast<uint2*>((u16*)outp + oidx) = pk;
        } else if (EPI == 1) {
          uint2 pk; pk.x = cvt_pk_bf16(gelu_f(v[0]), gelu_f(v[1]));
          pk.y = cvt_pk_bf16(gelu_f(v[2]), gelu_f(v[3]));
          *reinterpret_cast<uint2*>((u16*)outp + oidx) = pk;
        } else {
          f32x4 rv = *reinterpret_cast<const f32x4*>((const float*)res + oidx);
          *reinterpret_cast<f32x4*>((float*)outp + oidx) = v + rv;
        }
      }
    }
  }
}

// ---------------- LayerNorm over C=256, one wave per token, bf16 out ----------------
__global__ __launch_bounds__(256)
void ln_kernel(const float* __restrict__ in, const float* __restrict__ g,
               const float* __restrict__ bt, u16* __restrict__ out, int M)
{
  const int wv = threadIdx.x >> 6, lane = threadIdx.x & 63;
  const int t = blockIdx.x * 4 + wv;
  if (t >= M) return;
  const float4 x = reinterpret_cast<const float4*>(in + (long)t*256)[lane];
  float s = x.x + x.y + x.z + x.w;
  float q = x.x*x.x + x.y*x.y + x.z*x.z + x.w*x.w;
#pragma unroll
  for (int o = 32; o > 0; o >>= 1) { s += __shfl_xor(s, o); q += __shfl_xor(q, o); }
  const float m  = s * (1.0f/256.0f);
  const float var = q * (1.0f/256.0f) - m*m;
  const float rs = rsqrtf(var + 1e-5f);
  const float4 gv = reinterpret_cast<const float4*>(g)[lane];
  const float4 bv = reinterpret_cast<const float4*>(bt)[lane];
  uint2 o4;
  o4.x = cvt_pk_bf16((x.x - m)*rs*gv.x + bv.x, (x.y - m)*rs*gv.y + bv.y);
  o4.y = cvt_pk_bf16((x.z - m)*rs*gv.z + bv.z, (x.w - m)*rs*gv.w + bv.w);
  *reinterpret_cast<uint2*>(out + (long)t*256 + lane*4) = o4;
}

// -------- fused per-head LN(k), LN(v) + kv[b,h] += k^T v / N (atomic f32) --------
__global__ __launch_bounds__(256)
void kv_kernel(const u16* __restrict__ QKV,
               const float* __restrict__ kg, const float* __restrict__ kb,
               const float* __restrict__ vg, const float* __restrict__ vb,
               float* __restrict__ kvout)
{
  const int bh = blockIdx.x, b = bh >> 3, h = bh & 7;
  const int tid = threadIdx.x;
  __shared__ u16 kls[256][32];
  __shared__ u16 vls[256][32];
  __shared__ float sg[4][32];
  if (tid < 32) {
    sg[0][tid] = kg[h*32 + tid];
    sg[1][tid] = kb[h*32 + tid];
    sg[2][tid] = vg[h*32 + tid];
    sg[3][tid] = vb[h*32 + tid];
  }
  const int d = tid >> 3, e0 = (tid & 7) * 4;
  float a0=0, a1=0, a2=0, a3=0;

  for (int sub = 0; sub < 2; ++sub) {
    const int r = blockIdx.y * 512 + sub * 256 + tid;
    __syncthreads();
    if (r < NTOK) {
      const u16* rowp = QKV + (long)(b*NTOK + r)*768;
#pragma unroll
      for (int kv2 = 0; kv2 < 2; ++kv2) {
        const u16* p = rowp + (kv2 ? 512 : 256) + h*32;
        float xv[32]; float s = 0.f;
#pragma unroll
        for (int q4 = 0; q4 < 4; ++q4) {
          u16x8 u = *reinterpret_cast<const u16x8*>(p + q4*8);
#pragma unroll
          for (int j = 0; j < 8; ++j) { float f = bf2f(u[j]); xv[q4*8+j] = f; s += f; }
        }
        const float m = s * (1.0f/32.0f);
        float vv = 0.f;
#pragma unroll
        for (int j = 0; j < 32; ++j) { float d2 = xv[j]-m; vv += d2*d2; }
        const float rs = rsqrtf(vv*(1.0f/32.0f) + 1e-5f);
        const float* gg = sg[kv2 ? 2 : 0];
        const float* bb = sg[kv2 ? 3 : 1];
        u16 (*dst)[32] = kv2 ? vls : kls;
#pragma unroll
        for (int j = 0; j < 32; ++j) dst[tid][j] = f2bf((xv[j]-m)*rs*gg[j] + bb[j]);
      }
    } else {
#pragma unroll
      for (int j = 0; j < 32; ++j) { kls[tid][j] = 0; vls[tid][j] = 0; }
    }
    __syncthreads();
#pragma unroll 4
    for (int rr = 0; rr < 256; ++rr) {
      const float kd = bf2f(kls[rr][d]);
      u16x4 v4 = *reinterpret_cast<const u16x4*>(&vls[rr][e0]);
      a0 += kd * bf2f(v4[0]); a1 += kd * bf2f(v4[1]);
      a2 += kd * bf2f(v4[2]); a3 += kd * bf2f(v4[3]);
    }
  }
  const float sc = 1.0f / (float)NTOK;
  float* o = kvout + (long)bh*1024 + d*32 + e0;
  atomicAdd(o+0, a0*sc); atomicAdd(o+1, a1*sc);
  atomicAdd(o+2, a2*sc); atomicAdd(o+3, a3*sc);
}

// -------- Wo_eff_t[b][c][r=h*32+d] = sum_e kv[b,h,d,e] * Wo[h*32+e][c] (bf16, B^T layout) -----
__global__ __launch_bounds__(256)
void woeff_kernel(const float* __restrict__ kv, const float* __restrict__ Wo,
                  u16* __restrict__ Woet)
{
  const int b = blockIdx.x >> 8, c = blockIdx.x & 255;
  const int rtid = threadIdx.x;
  const int h = rtid >> 5, dd = rtid & 31;
  const float* kvp = kv + ((long)(b*8 + h)*32 + dd)*32;
  float s = 0.f;
#pragma unroll 8
  for (int e = 0; e < 32; ++e) s += kvp[e] * Wo[(h*32 + e)*256 + c];
  Woet[(long)(b*256 + c)*256 + rtid] = f2bf(s);
}

// ---------------- prep kernels ----------------
__global__ void zero_f32(float* p, int n) {
  int i = blockIdx.x*blockDim.x + threadIdx.x; if (i < n) p[i] = 0.f;
}
__global__ void concat_bias(const float* bq, const float* bk, const float* bv, float* o) {
  int i = threadIdx.x;
  o[i] = (i < 256) ? bq[i] : ((i < 512) ? bk[i-256] : bv[i-512]);
}
__global__ __launch_bounds__(256)
void transpose_cvt(const float* __restrict__ src, u16* __restrict__ dst, int R, int C) {
  __shared__ float t[32][33];
  const int tc = blockIdx.x * 32, tr = blockIdx.y * 32;
  const int lx = threadIdx.x & 31, ly = threadIdx.x >> 5;
#pragma unroll
  for (int i = 0; i < 32; i += 8)
    t[ly + i][lx] = src[(long)(tr + ly + i)*C + tc + lx];
  __syncthreads();
#pragma unroll
  for (int i = 0; i < 32; i += 8)
    dst[(long)(tc + ly + i)*R + tr + lx] = f2bf(t[lx][ly + i]);
}

// ---------------- launch ----------------
extern "C" void kernel_launch(void* const* d_in, const int* in_sizes, int n_in,
                              void* d_out, int out_size, void* d_ws, size_t ws_size,
                              hipStream_t stream)
{
  const float* fx    = (const float*)d_in[0];
  const float* ln1_g = (const float*)d_in[1];
  const float* ln1_b = (const float*)d_in[2];
  const float* Wq = (const float*)d_in[3];
  const float* bq = (const float*)d_in[4];
  const float* Wk = (const float*)d_in[5];
  const float* bk = (const float*)d_in[6];
  const float* Wv = (const float*)d_in[7];
  const float* bv = (const float*)d_in[8];
  const float* Wo = (const float*)d_in[9];
  const float* bo = (const float*)d_in[10];
  const float* kg  = (const float*)d_in[11];
  const float* kbb = (const float*)d_in[12];
  const float* vg  = (const float*)d_in[13];
  const float* vbb = (const float*)d_in[14];
  const float* ln2_g = (const float*)d_in[15];
  const float* ln2_b = (const float*)d_in[16];
  const float* W1 = (const float*)d_in[17];
  const float* b1 = (const float*)d_in[18];
  const float* W2 = (const float*)d_in[19];
  const float* b2 = (const float*)d_in[20];
  float* outF = (float*)d_out;

  char* ws = (char*)d_ws;
  size_t off = 0;
  auto alloc = [&](size_t bytes) { char* p = ws + off; off += (bytes + 255) & ~(size_t)255; return p; };
  u16* bufX   = (u16*)alloc((size_t)MROWS*256*2);
  u16* bufQKV = (u16*)alloc((size_t)MROWS*768*2);
  u16* bufH   = (u16*)alloc((size_t)MROWS*1024*2);
  u16* Wqkv_t = (u16*)alloc(768*256*2);
  u16* W1_t   = (u16*)alloc(1024*256*2);
  u16* W2_t   = (u16*)alloc(256*1024*2);
  u16* Woe_t  = (u16*)alloc((size_t)8*256*256*2);
  float* kvb  = (float*)alloc((size_t)64*1024*4);
  float* bqkv = (float*)alloc(768*4);
  (void)ws_size; (void)out_size; (void)n_in; (void)in_sizes;

  // prep
  zero_f32<<<256, 256, 0, stream>>>(kvb, 65536);
  concat_bias<<<1, 768, 0, stream>>>(bq, bk, bv, bqkv);
  transpose_cvt<<<dim3(8,8),  256, 0, stream>>>(Wq, Wqkv_t,          256, 256);
  transpose_cvt<<<dim3(8,8),  256, 0, stream>>>(Wk, Wqkv_t + 65536,  256, 256);
  transpose_cvt<<<dim3(8,8),  256, 0, stream>>>(Wv, Wqkv_t + 131072, 256, 256);
  transpose_cvt<<<dim3(32,8), 256, 0, stream>>>(W1, W1_t, 256, 1024);
  transpose_cvt<<<dim3(8,32), 256, 0, stream>>>(W2, W2_t, 1024, 256);

  // x = LN1(fx)
  ln_kernel<<<MTOT/4, 256, 0, stream>>>(fx, ln1_g, ln1_b, bufX, MTOT);

  // QKV = x @ [Wq|Wk|Wv] + [bq|bk|bv]
  gemm_bt<0><<<dim3(RT_FULL, 6, 1), 256, 0, stream>>>(
      bufX, 256, Wqkv_t, 256, 0, bqkv, nullptr, bufQKV, 768, 256, 1<<30, 0);

  // kv[b,h] = LN(k)^T LN(v) / N
  kv_kernel<<<dim3(64, 15), 256, 0, stream>>>(bufQKV, kg, kbb, vg, vbb, kvb);

  // Wo_eff per batch
  woeff_kernel<<<2048, 256, 0, stream>>>(kvb, Wo, Woe_t);

  // d_out = fx + q @ Wo_eff[b] + bo   (batched GEMM)
  gemm_bt<2><<<dim3(RT_BATCH, 2, 8), 256, 0, stream>>>(
      bufQKV, 768, Woe_t, 256, 65536, bo, fx, outF, 256, 256, NTOK, NTOK);

  // x2 = LN2(d_out)
  ln_kernel<<<MTOT/4, 256, 0, stream>>>(outF, ln2_g, ln2_b, bufX, MTOT);

  // H = gelu(x2 @ W1 + b1)
  gemm_bt<1><<<dim3(RT_FULL, 8, 1), 256, 0, stream>>>(
      bufX, 256, W1_t, 256, 0, b1, nullptr, bufH, 1024, 256, 1<<30, 0);

  // d_out = d_out + H @ W2 + b2
  gemm_bt<2><<<dim3(RT_FULL, 2, 1), 256, 0, stream>>>(
      bufH, 1024, W2_t, 1024, 0, b2, outF, outF, 256, 1024, MTOT, 0);
}